// Round 2
// 295.048 us; speedup vs baseline: 1.0417x; 1.0417x over previous
//
#include <hip/hip_runtime.h>
#include <math.h>

// Problem constants (x: [2048, 2048, 3, 3] f32, bits=8)
// channel stride = h*w = 9 floats; group-block = 8 channels * 9 = 72
// consecutive floats; n = 37,748,736 floats = 524,288 group-blocks.
#define HW        9
#define GROUP     8
#define KEEP      4
#define DELTA     127.0f
#define INV_DELTA (1.0f / 127.0f)
#define GB_FLOATS 72

// Wave-tile geometry: each 64-lane wave owns 32 contiguous group-blocks.
#define GB_TILE   32
#define TILE_F    (GB_TILE * GB_FLOATS)   // 2304 floats = 9216 B per wave
#define TILE_CH   (TILE_F / 256)          // 9 chunks of 1024 B (64 lanes x 16 B)
#define CELLS     (GB_TILE * HW)          // 288 cells per tile (4.5 per lane)
#define WPB       4                       // waves per 256-thread block

typedef float f32x4 __attribute__((ext_vector_type(4)));  // clang-native vec
                                                          // (nontemporal builtin
                                                          // rejects HIP float4)

// ---------------- Kernel 1: global max|x| ----------------
__global__ void maxabs_kernel(const float4* __restrict__ x, unsigned* __restrict__ ws, int n4) {
    __shared__ float red[4];
    float m = 0.0f;
    int stride = gridDim.x * blockDim.x;
    #pragma unroll 4
    for (int i = blockIdx.x * blockDim.x + threadIdx.x; i < n4; i += stride) {
        float4 v = x[i];
        m = fmaxf(m, fmaxf(fmaxf(fabsf(v.x), fabsf(v.y)),
                           fmaxf(fabsf(v.z), fabsf(v.w))));
    }
    #pragma unroll
    for (int off = 32; off > 0; off >>= 1)
        m = fmaxf(m, __shfl_down(m, off, 64));
    int wave = threadIdx.x >> 6;
    if ((threadIdx.x & 63) == 0) red[wave] = m;
    __syncthreads();
    if (threadIdx.x == 0) {
        float b = fmaxf(fmaxf(red[0], red[1]), fmaxf(red[2], red[3]));
        atomicMax(ws, __float_as_uint(b));   // |x|>=0: float bit order == uint order
    }
}

// Cold bit-exact reference path (identical to the passing kernel):
// t = (float)tanh(double x); y = t/M (f32 div); z = y*127; rint.
__device__ __attribute__((noinline)) float ref_rz(float xx, float M) {
    float td = (float)tanh((double)xx);
    float y  = td / M;
    return rintf(y * DELTA);
}

// Fast f32 tanh. Poly (|x|<=0.5): Taylor odd series through x^11,
// rel err <= ~2.5e-7. Exp form else: (E-1)/(E+1) with native exp + NR rcp.
__device__ __forceinline__ float fast_tanh(float x) {
    float ax  = fabsf(x);
    float axc = fminf(ax, 10.0f);
    float E   = __expf(2.0f * axc);
    float num = E - 1.0f;
    float den = E + 1.0f;
    float r0  = __builtin_amdgcn_rcpf(den);
    float r   = r0 * fmaf(-den, r0, 2.0f);      // one Newton step
    float tl  = copysignf(num * r, x);
    float s = x * x;
    float p = fmaf(s, 0.0035921280f, -0.0088632358f);
    p = fmaf(s, p, 0.021869488f);
    p = fmaf(s, p, -0.053968254f);
    p = fmaf(s, p, 0.13333334f);
    p = fmaf(s, p, -0.33333334f);
    float ts = fmaf(x * s, p, x);
    return (ax <= 0.5f) ? ts : tl;
}

// ---------------- Kernel 2: quantize + group top-4 mask ----------------
// Wave-coalesced version. Each wave:
//   1) stages its 9216-B tile global->LDS via global_load_lds (width 16,
//      fully coalesced, linear LDS layout = exactly what the HW requires),
//   2) waits vmcnt(0) (wave-private tile -> NO barriers needed; DS ops
//      retire in order within a wave),
//   3) each lane processes one (group-block, hw) cell per round: 8 scalar
//      ds_read_b32 at 36-B stride (~2-way bank aliasing = free), quantize +
//      stable top-4 in registers, 8 ds_write_b32 back,
//   4) coalesced ds_read_b128 -> nontemporal global_store_dwordx4 (don't
//      let the write stream evict x from L3 -- maxabs just warmed it).
// Numerics are byte-identical to the previous passing kernel.
__global__ __launch_bounds__(256, 4) void quant_kernel(const float* __restrict__ x,
                             float* __restrict__ out,
                             const unsigned* __restrict__ ws,
                             int n_gb) {
    __shared__ float lds[WPB][TILE_F];   // 36,864 B -> 4 blocks/CU
    __shared__ float sM, sC;
    if (threadIdx.x == 0) {
        // M = max|tanh(x)| = tanh(max|x|) (tanh odd+monotone; RNE symmetric)
        float mm = (float)tanh((double)__uint_as_float(*ws));
        sM = mm;
        sC = (float)(127.0 / (double)mm);
    }
    __syncthreads();                      // the only barrier in this kernel
    float M = sM, C = sC;

    const int wv   = threadIdx.x >> 6;
    const int lane = threadIdx.x & 63;
    const int tile = blockIdx.x * WPB + wv;
    if (tile * GB_TILE >= n_gb) return;   // exact fit for this shape (524288/32 = 16384 waves)

    const size_t base = (size_t)tile * TILE_F;
    const float* src  = x + base;
    float* ldsw       = &lds[wv][0];

    // ---- stage global -> LDS: 9 x (64 lanes x 16 B), linear ----
    #pragma unroll
    for (int k = 0; k < TILE_CH; ++k) {
        __builtin_amdgcn_global_load_lds(
            (__attribute__((address_space(1))) void*)(src + k * 256 + lane * 4),
            (__attribute__((address_space(3))) void*)(ldsw + k * 256),
            16, 0, 0);
    }
    asm volatile("s_waitcnt vmcnt(0)" ::: "memory");
    __builtin_amdgcn_sched_barrier(0);

    // ---- compute: one cell (8 channels at stride 9) per lane per round ----
    for (int c = 0; c < (CELLS + 63) / 64; ++c) {
        int ci = lane + 64 * c;           // cell id within tile
        if (ci < CELLS) {                 // only masks half of round 4
            int gb = ci / 9;              // compiler emits magic-mul
            int hw = ci - gb * 9;
            float* cell = ldsw + gb * GB_FLOATS + hw;

            float v8[GROUP], a8[GROUP];
            #pragma unroll
            for (int j = 0; j < GROUP; ++j) {
                float xx = cell[9 * j];
                float t  = fast_tanh(xx);
                float z  = t * C;
                float rz = rintf(z);                 // numpy round: half-to-even
                float d  = 0.5f - fabsf(z - rz);     // distance to nearest half-int
                if (d < fmaf(2e-6f, fabsf(z), 5e-7f))
                    rz = ref_rz(xx, M);              // cold, bit-exact chain
                v8[j] = rz;
                a8[j] = fabsf(rz);
            }
            // stable top-4: rank[j] = #{i beating j}; i<j beats iff a_i >= a_j
            int rank[GROUP] = {0, 0, 0, 0, 0, 0, 0, 0};
            #pragma unroll
            for (int i = 0; i < GROUP; ++i) {
                #pragma unroll
                for (int j = i + 1; j < GROUP; ++j) {
                    bool ge = (a8[i] >= a8[j]);
                    rank[j] += ge ? 1 : 0;
                    rank[i] += ge ? 0 : 1;
                }
            }
            #pragma unroll
            for (int j = 0; j < GROUP; ++j)
                cell[9 * j] = (rank[j] < KEEP) ? (v8[j] * INV_DELTA) : 0.0f;
        }
    }
    __builtin_amdgcn_sched_barrier(0);

    // ---- coalesced LDS -> global, nontemporal ----
    f32x4* dst4       = (f32x4*)(out + base);
    const f32x4* l4   = (const f32x4*)ldsw;
    #pragma unroll
    for (int k = 0; k < TILE_CH; ++k) {
        __builtin_nontemporal_store(l4[k * 64 + lane], &dst4[k * 64 + lane]);
    }
}

extern "C" void kernel_launch(void* const* d_in, const int* in_sizes, int n_in,
                              void* d_out, int out_size, void* d_ws, size_t ws_size,
                              hipStream_t stream) {
    const float* x = (const float*)d_in[0];
    float* out = (float*)d_out;
    unsigned* ws = (unsigned*)d_ws;

    int n = in_sizes[0];                 // 37,748,736
    int n4 = n / 4;
    int n_gb = n / GB_FLOATS;            // 524,288

    hipMemsetAsync(ws, 0, sizeof(unsigned), stream);

    maxabs_kernel<<<2048, 256, 0, stream>>>((const float4*)x, ws, n4);

    int blocks_q = (n_gb + GB_TILE * WPB - 1) / (GB_TILE * WPB);   // 4096
    quant_kernel<<<blocks_q, 256, 0, stream>>>(x, out, ws, n_gb);
}